// Round 1
// baseline (4202.631 us; speedup 1.0000x reference)
//
#include <hip/hip_runtime.h>
#include <hip/hip_bf16.h>

// ---------------- problem constants ----------------
#define TT   256   // sequence length
#define BB   64    // batch
#define EE   256   // input embedding
#define HH   512   // hidden
#define KTAG 32    // number of tags
#define START_TAG 30
#define END_TAG   31

// ---------------- recurrence decomposition ----------------
#define NSL  32            // workgroups per direction; each owns 16 hidden units
#define NWG  (2 * NSL)     // total workgroups (both directions in one grid)
#define NKK  24            // K-steps of 32: 16 for h (K=512) + 8 for x (K=256)
#define LDA  776           // padded LDS row (bf16 elems); 776*2B = 1552B (16B multiple)

typedef __attribute__((ext_vector_type(8))) __bf16 bf16x8;
typedef __attribute__((ext_vector_type(4))) __bf16 bf16x4;
typedef __attribute__((ext_vector_type(4))) float  f32x4;

// ---------------- workspace layout (bytes) ----------------
#define OFF_XB  ((size_t)0)                              // Xb: TT*BB*EE bf16 = 8 MiB
#define OFF_H   ((size_t)TT * BB * EE * 2)               // h:  2*TT*BB*HH bf16 = 32 MiB
#define OFF_EM  (OFF_H + (size_t)2 * TT * BB * HH * 2)   // em: TT*BB*KTAG f32 = 2 MiB
#define OFF_CNT (OFF_EM + (size_t)TT * BB * KTAG * 4)    // cnt: 2*TT ints
#define WS_NEED (OFF_CNT + (size_t)2 * TT * 4)

// ============================================================
// K0: X (fp32, [b][t][e]) -> Xb (bf16, [t][b][e])
// ============================================================
__global__ __launch_bounds__(256) void prep_x(const float* __restrict__ X,
                                              __bf16* __restrict__ Xb) {
    int i = blockIdx.x * 256 + threadIdx.x;   // one thread = 4 output elems
    int o = i * 4;                            // flat index into Xb
    int e  = o & (EE - 1);
    int tb = o >> 8;                          // EE = 256
    int b  = tb & (BB - 1);
    int t  = tb >> 6;                         // BB = 64
    const float4 v = *reinterpret_cast<const float4*>(X + ((size_t)b * TT + t) * EE + e);
    bf16x4 r;
    r[0] = (__bf16)v.x; r[1] = (__bf16)v.y; r[2] = (__bf16)v.z; r[3] = (__bf16)v.w;
    *reinterpret_cast<bf16x4*>(Xb + o) = r;
}

// ============================================================
// K1: persistent cooperative BiLSTM recurrence (bf16 MFMA).
// Grid = 64 WGs x 256 threads. WG w: direction d = w>>5, slice sl = w&31.
// Each WG owns 16 hidden units (64 gate rows). Per step it computes
// gates = [h_prev | x_t] (64x768, in LDS, bf16) @ W^T (768x64, in VGPRs),
// via mfma_f32_16x16x32_bf16; wave q owns units 4q..4q+3 (16 cols).
// Cross-WG h exchange through global memory + per-(dir,step) counters.
// ============================================================
__global__ __launch_bounds__(256, 1) void rec_kernel(
    const __bf16* __restrict__ Xb,
    const float* __restrict__ Wih_f, const float* __restrict__ Whh_f,
    const float* __restrict__ bih_f, const float* __restrict__ bhh_f,
    const float* __restrict__ Wih_b, const float* __restrict__ Whh_b,
    const float* __restrict__ bih_b, const float* __restrict__ bhh_b,
    __bf16* __restrict__ h, int* __restrict__ cnt) {
    __shared__ __bf16 A[BB * LDA];   // 99,328 B

    const int wg  = blockIdx.x;
    const int d   = wg >> 5;         // 0 = fwd, 1 = bwd
    const int sl  = wg & 31;
    const int U0  = sl * 16;         // first hidden unit of this WG
    const int tid = threadIdx.x;
    const int q   = tid >> 6;        // wave id (0..3)
    const int l   = tid & 63;        // lane
    const int c   = l & 15;          // MFMA col / A row-in-tile
    const int kch = l >> 4;          // MFMA k-chunk (0..3)

    const float* Wih = d ? Wih_b : Wih_f;
    const float* Whh = d ? Whh_b : Whh_f;
    const float* bih = d ? bih_b : bih_f;
    const float* bhh = d ? bhh_b : bhh_f;
    __bf16* hd = h + (size_t)d * TT * BB * HH;

    // this lane's gate row (column c of the wave's N=16 tile):
    // c = g*4 + u', unit = U0 + 4*q + u', global row = g*512 + unit
    const int g4  = c >> 2;
    const int up  = c & 3;
    const int row = g4 * HH + U0 + 4 * q + up;

    // ---- one-time: load B fragments (weights, bf16) into registers ----
    // B[k][c] = Whh[row][k] for k<512, Wih[row][k-512] otherwise.
    bf16x8 Bf[NKK];
#pragma unroll
    for (int kk = 0; kk < NKK; ++kk) {
        bf16x8 bv;
#pragma unroll
        for (int j = 0; j < 8; ++j) {
            int kb = kch * 8 + j;
            float w = (kk < 16) ? Whh[(size_t)row * HH + kk * 32 + kb]
                                : Wih[(size_t)row * EE + (kk - 16) * 32 + kb];
            bv[j] = (__bf16)w;
        }
        Bf[kk] = bv;
    }
    const float bias = bih[row] + bhh[row];

    // cell state for (b = mt*16 + kch*4 + r, unit = U0+4q+c); valid in lanes c<4
    f32x4 cs[4];
#pragma unroll
    for (int mt = 0; mt < 4; ++mt) cs[mt] = (f32x4){0.f, 0.f, 0.f, 0.f};

    for (int s = 0; s < TT; ++s) {
        const int t  = d ? (TT - 1 - s) : s;
        const int tp = d ? (t + 1) : (t - 1);

        // wait for all WGs of this direction to finish step s-1
        if (s > 0 && tid == 0) {
            while (__hip_atomic_load(&cnt[d * TT + s - 1], __ATOMIC_ACQUIRE,
                                     __HIP_MEMORY_SCOPE_AGENT) < NSL)
                __builtin_amdgcn_s_sleep(1);
        }
        __syncthreads();

        // ---- stage A = [h_prev (512) | x_t (256)] into LDS (bf16) ----
        if (s > 0) {
            const __bf16* hp = hd + (size_t)tp * BB * HH;
#pragma unroll
            for (int it = 0; it < 16; ++it) {
                int idx = tid + it * 256;
                int b = idx >> 6, ch = idx & 63;
                *reinterpret_cast<bf16x8*>(&A[b * LDA + ch * 8]) =
                    *reinterpret_cast<const bf16x8*>(hp + (size_t)b * HH + ch * 8);
            }
        }
        {
            const __bf16* xp = Xb + (size_t)t * BB * EE;
#pragma unroll
            for (int it = 0; it < 8; ++it) {
                int idx = tid + it * 256;
                int b = idx >> 5, ch = idx & 31;
                *reinterpret_cast<bf16x8*>(&A[b * LDA + 512 + ch * 8]) =
                    *reinterpret_cast<const bf16x8*>(xp + (size_t)b * EE + ch * 8);
            }
        }
        __syncthreads();

        // ---- MFMA: acc[mt] (16b x 16 gate-rows) over K ----
        f32x4 acc[4];
#pragma unroll
        for (int mt = 0; mt < 4; ++mt) acc[mt] = (f32x4){bias, bias, bias, bias};

        if (s == 0) {   // h_prev == 0: only the x part (kk = 16..23)
#pragma unroll
            for (int mt = 0; mt < 4; ++mt) {
                const __bf16* ab = &A[(mt * 16 + c) * LDA + kch * 8];
#pragma unroll
                for (int kk = 16; kk < NKK; ++kk) {
                    bf16x8 a = *reinterpret_cast<const bf16x8*>(ab + kk * 32);
                    acc[mt] = __builtin_amdgcn_mfma_f32_16x16x32_bf16(a, Bf[kk], acc[mt], 0, 0, 0);
                }
            }
        } else {
#pragma unroll
            for (int mt = 0; mt < 4; ++mt) {
                const __bf16* ab = &A[(mt * 16 + c) * LDA + kch * 8];
#pragma unroll
                for (int kk = 0; kk < NKK; ++kk) {
                    bf16x8 a = *reinterpret_cast<const bf16x8*>(ab + kk * 32);
                    acc[mt] = __builtin_amdgcn_mfma_f32_16x16x32_bf16(a, Bf[kk], acc[mt], 0, 0, 0);
                }
            }
        }

        // ---- gather i,f,g,o per (b,unit) via xor-shuffles; activations; h out ----
        __bf16* ho = hd + (size_t)t * BB * HH;
#pragma unroll
        for (int mt = 0; mt < 4; ++mt) {
#pragma unroll
            for (int r = 0; r < 4; ++r) {
                float v   = acc[mt][r];
                float t4  = __shfl_xor(v, 4);    // gate 1 (f) for lanes c<4
                float t8  = __shfl_xor(v, 8);    // gate 2 (g)
                float t12 = __shfl_xor(t4, 8);   // gate 3 (o)
                float ig = 1.f / (1.f + __expf(-v));
                float fg = 1.f / (1.f + __expf(-t4));
                float e2 = __expf(2.f * t8);
                float gg = 1.f - 2.f / (e2 + 1.f);      // tanh
                float og = 1.f / (1.f + __expf(-t12));
                float cn = fg * cs[mt][r] + ig * gg;
                cs[mt][r] = cn;
                float e2c = __expf(2.f * cn);
                float th  = 1.f - 2.f / (e2c + 1.f);
                float hv  = og * th;
                if (c < 4) {
                    int b = mt * 16 + kch * 4 + r;
                    ho[(size_t)b * HH + U0 + 4 * q + c] = (__bf16)hv;
                }
            }
        }

        __threadfence();
        __syncthreads();
        if (tid == 0)
            __hip_atomic_fetch_add(&cnt[d * TT + s], 1, __ATOMIC_RELEASE,
                                   __HIP_MEMORY_SCOPE_AGENT);
    }
}

// ============================================================
// K2: emissions em[t][b][k] = [hf(t),hb(t)] . W_out[:,k] + b_out[k]
// One WG per t; thread (b8,k): k = tid&31, 8 batches each.
// ============================================================
__global__ __launch_bounds__(256) void em_kernel(const __bf16* __restrict__ h,
                                                 const float* __restrict__ W_out,
                                                 const float* __restrict__ b_out,
                                                 float* __restrict__ em) {
    const int t  = blockIdx.x;
    const int k  = threadIdx.x & 31;
    const int b8 = threadIdx.x >> 5;

    float acc[8];
#pragma unroll
    for (int i = 0; i < 8; ++i) acc[i] = b_out[k];

#pragma unroll
    for (int src = 0; src < 2; ++src) {
        const __bf16* hr = h + ((size_t)src * TT + t) * BB * HH;
        const float*  W  = W_out + (size_t)src * HH * KTAG;
        for (int jc = 0; jc < HH / 8; ++jc) {
            float w[8];
#pragma unroll
            for (int jj = 0; jj < 8; ++jj) w[jj] = W[(jc * 8 + jj) * KTAG + k];
#pragma unroll
            for (int i = 0; i < 8; ++i) {
                bf16x8 hv = *reinterpret_cast<const bf16x8*>(
                    hr + (size_t)(b8 * 8 + i) * HH + jc * 8);
#pragma unroll
                for (int jj = 0; jj < 8; ++jj) acc[i] += (float)hv[jj] * w[jj];
            }
        }
    }
#pragma unroll
    for (int i = 0; i < 8; ++i)
        em[((size_t)t * BB + (b8 * 8 + i)) * KTAG + k] = acc[i];
}

// ============================================================
// K3: CRF — sentence score + log-partition; out[b] = logZ - score.
// One WG (1 wave) per batch element. lane: j = lane&31, half = lane>>5.
// ============================================================
__global__ __launch_bounds__(64) void crf_kernel(const float* __restrict__ em,
                                                 const int* __restrict__ tags,
                                                 const float* __restrict__ masks,
                                                 const float* __restrict__ trans,
                                                 float* __restrict__ out) {
    __shared__ float tr[KTAG * KTAG];
    __shared__ float al[64];
    const int b    = blockIdx.x;
    const int lane = threadIdx.x;

#pragma unroll
    for (int ii = 0; ii < 16; ++ii) tr[lane + ii * 64] = trans[lane + ii * 64];
    __syncthreads();

    // ---- sentence (gold-path) score ----
    float part = 0.f, msum = 0.f;
    for (int t = lane; t < TT; t += 64) {
        int tg = tags[b * TT + t];
        float e = em[((size_t)t * BB + b) * KTAG + tg];
        if (t == 0) {
            part += tr[START_TAG * KTAG + tg] + e;
        } else {
            int tgp = tags[b * TT + t - 1];
            float m = masks[b * TT + t];
            part += m * (e + tr[tgp * KTAG + tg]);
        }
        msum += masks[b * TT + t];
    }
#pragma unroll
    for (int off = 32; off; off >>= 1) {
        part += __shfl_xor(part, off);
        msum += __shfl_xor(msum, off);
    }
    int   last_idx = (int)(msum + 0.5f) - 1;
    int   last_tag = tags[b * TT + last_idx];
    float score    = part + tr[last_tag * KTAG + END_TAG];

    // ---- log partition (forward algorithm) ----
    const int j    = lane & 31;
    const int half = lane >> 5;
    float alpha = tr[START_TAG * KTAG + j] + em[(size_t)b * KTAG + j];  // t = 0
    for (int t = 1; t < TT; ++t) {
        al[lane] = alpha;
        __syncthreads();
        float v[16], mx = -1e30f;
#pragma unroll
        for (int ii = 0; ii < 16; ++ii) {
            int i = half * 16 + ii;
            v[ii] = al[i] + tr[i * KTAG + j];
            mx = fmaxf(mx, v[ii]);
        }
        float sexp = 0.f;
#pragma unroll
        for (int ii = 0; ii < 16; ++ii) sexp += __expf(v[ii] - mx);
        float mo = __shfl_xor(mx, 32);
        float so = __shfl_xor(sexp, 32);
        float m2 = fmaxf(mx, mo);
        float st = sexp * __expf(mx - m2) + so * __expf(mo - m2);
        float e  = em[((size_t)t * BB + b) * KTAG + j];
        float na = e + m2 + __logf(st);
        float m  = masks[b * TT + t];
        alpha = na * m + alpha * (1.f - m);
        __syncthreads();
    }
    alpha += tr[j * KTAG + END_TAG];
    float m = alpha, ssum = 1.f;
#pragma unroll
    for (int off = 1; off < 32; off <<= 1) {
        float mo = __shfl_xor(m, off);
        float so = __shfl_xor(ssum, off);
        float m2 = fmaxf(m, mo);
        ssum = ssum * __expf(m - m2) + so * __expf(mo - m2);
        m = m2;
    }
    float logZ = m + __logf(ssum);
    if (lane == 0) out[b] = logZ - score;
}

// ============================================================
extern "C" void kernel_launch(void* const* d_in, const int* in_sizes, int n_in,
                              void* d_out, int out_size, void* d_ws, size_t ws_size,
                              hipStream_t stream) {
    const float* X     = (const float*)d_in[0];
    const int*   tags  = (const int*)d_in[1];
    const float* masks = (const float*)d_in[2];
    const float* Wih_f = (const float*)d_in[3];
    const float* Whh_f = (const float*)d_in[4];
    const float* bih_f = (const float*)d_in[5];
    const float* bhh_f = (const float*)d_in[6];
    const float* Wih_b = (const float*)d_in[7];
    const float* Whh_b = (const float*)d_in[8];
    const float* bih_b = (const float*)d_in[9];
    const float* bhh_b = (const float*)d_in[10];
    const float* W_out = (const float*)d_in[11];
    const float* b_out = (const float*)d_in[12];
    const float* trans = (const float*)d_in[13];
    float* out = (float*)d_out;

    if (ws_size < WS_NEED) return;  // fail cleanly rather than corrupt

    char*   ws  = (char*)d_ws;
    __bf16* Xb  = (__bf16*)(ws + OFF_XB);
    __bf16* h   = (__bf16*)(ws + OFF_H);
    float*  em  = (float*)(ws + OFF_EM);
    int*    cnt = (int*)(ws + OFF_CNT);

    hipMemsetAsync(cnt, 0, 2 * TT * sizeof(int), stream);

    prep_x<<<dim3((TT * BB * EE / 4) / 256), dim3(256), 0, stream>>>(X, Xb);

    void* args[] = {(void*)&Xb,
                    (void*)&Wih_f, (void*)&Whh_f, (void*)&bih_f, (void*)&bhh_f,
                    (void*)&Wih_b, (void*)&Whh_b, (void*)&bih_b, (void*)&bhh_b,
                    (void*)&h, (void*)&cnt};
    hipLaunchCooperativeKernel(rec_kernel, dim3(NWG), dim3(256), args, 0, stream);

    em_kernel<<<dim3(TT), dim3(256), 0, stream>>>(h, W_out, b_out, em);
    crf_kernel<<<dim3(BB), dim3(64), 0, stream>>>(em, tags, masks, trans, out);
}

// Round 2
// 4150.974 us; speedup vs baseline: 1.0124x; 1.0124x over previous
//
#include <hip/hip_runtime.h>
#include <hip/hip_bf16.h>

// ---------------- problem constants ----------------
#define TT   256   // sequence length
#define BB   64    // batch
#define EE   256   // input embedding
#define HH   512   // hidden
#define KTAG 32    // number of tags
#define START_TAG 30
#define END_TAG   31

// ---------------- recurrence decomposition ----------------
#define NSL  32            // workgroups per direction; each owns 16 hidden units
#define NWG  (2 * NSL)     // total workgroups (both directions in one grid)
#define NKK  24            // K-steps of 32: 16 for h (K=512) + 8 for x (K=256)
#define LDA  776           // padded LDS row (bf16 elems); 776*2B = 1552B (16B multiple)

typedef __attribute__((ext_vector_type(8))) __bf16 bf16x8;
typedef __attribute__((ext_vector_type(4))) __bf16 bf16x4;
typedef __attribute__((ext_vector_type(4))) float  f32x4;
typedef unsigned long long u64;

// ---------------- workspace layout (bytes) ----------------
#define OFF_XB  ((size_t)0)                              // Xb: TT*BB*EE bf16 = 8 MiB
#define OFF_H   ((size_t)TT * BB * EE * 2)               // h:  2*TT*BB*HH bf16 = 32 MiB
#define OFF_EM  (OFF_H + (size_t)2 * TT * BB * HH * 2)   // em: TT*BB*KTAG f32 = 2 MiB
#define OFF_CNT (OFF_EM + (size_t)TT * BB * KTAG * 4)    // cnt: 2*TT ints
#define WS_NEED (OFF_CNT + (size_t)2 * TT * 4)

// ============================================================
// K0: X (fp32, [b][t][e]) -> Xb (bf16, [t][b][e])
// ============================================================
__global__ __launch_bounds__(256) void prep_x(const float* __restrict__ X,
                                              __bf16* __restrict__ Xb) {
    int i = blockIdx.x * 256 + threadIdx.x;   // one thread = 4 output elems
    int o = i * 4;                            // flat index into Xb
    int e  = o & (EE - 1);
    int tb = o >> 8;                          // EE = 256
    int b  = tb & (BB - 1);
    int t  = tb >> 6;                         // BB = 64
    const float4 v = *reinterpret_cast<const float4*>(X + ((size_t)b * TT + t) * EE + e);
    bf16x4 r;
    r[0] = (__bf16)v.x; r[1] = (__bf16)v.y; r[2] = (__bf16)v.z; r[3] = (__bf16)v.w;
    *reinterpret_cast<bf16x4*>(Xb + o) = r;
}

// ============================================================
// K1: persistent cooperative BiLSTM recurrence (bf16 MFMA).
// Cross-WG h exchange via agent-scope RELAXED atomics (L2-bypassing,
// coherent at the device coherence point) — NO buffer_wbl2/buffer_inv
// in the step loop.
// ============================================================
__global__ __launch_bounds__(256, 1) void rec_kernel(
    const __bf16* __restrict__ Xb,
    const float* __restrict__ Wih_f, const float* __restrict__ Whh_f,
    const float* __restrict__ bih_f, const float* __restrict__ bhh_f,
    const float* __restrict__ Wih_b, const float* __restrict__ Whh_b,
    const float* __restrict__ bih_b, const float* __restrict__ bhh_b,
    __bf16* __restrict__ h, int* __restrict__ cnt) {
    __shared__ __bf16 A[BB * LDA];   // 99,328 B

    const int wg  = blockIdx.x;
    const int d   = wg >> 5;         // 0 = fwd, 1 = bwd
    const int sl  = wg & 31;
    const int U0  = sl * 16;         // first hidden unit of this WG
    const int tid = threadIdx.x;
    const int q   = tid >> 6;        // wave id (0..3)
    const int l   = tid & 63;        // lane
    const int c   = l & 15;          // MFMA col / A row-in-tile
    const int kch = l >> 4;          // MFMA k-chunk (0..3)

    const float* Wih = d ? Wih_b : Wih_f;
    const float* Whh = d ? Whh_b : Whh_f;
    const float* bih = d ? bih_b : bih_f;
    const float* bhh = d ? bhh_b : bhh_f;
    __bf16* hd = h + (size_t)d * TT * BB * HH;

    // this lane's gate row (column c of the wave's N=16 tile):
    // c = g*4 + u', unit = U0 + 4*q + u', global row = g*512 + unit
    const int g4  = c >> 2;
    const int up  = c & 3;
    const int row = g4 * HH + U0 + 4 * q + up;

    // ---- one-time: load B fragments (weights, bf16) into registers ----
    bf16x8 Bf[NKK];
#pragma unroll
    for (int kk = 0; kk < NKK; ++kk) {
        bf16x8 bv;
#pragma unroll
        for (int j = 0; j < 8; ++j) {
            int kb = kch * 8 + j;
            float w = (kk < 16) ? Whh[(size_t)row * HH + kk * 32 + kb]
                                : Wih[(size_t)row * EE + (kk - 16) * 32 + kb];
            bv[j] = (__bf16)w;
        }
        Bf[kk] = bv;
    }
    const float bias = bih[row] + bhh[row];

    // cell state for (b = mt*16 + kch*4 + r, unit = U0+4q+c); valid in lanes c<4
    f32x4 cs[4];
#pragma unroll
    for (int mt = 0; mt < 4; ++mt) cs[mt] = (f32x4){0.f, 0.f, 0.f, 0.f};

    for (int s = 0; s < TT; ++s) {
        const int t  = d ? (TT - 1 - s) : s;
        const int tp = d ? (t + 1) : (t - 1);

        // ---- stage x_t into LDS (no dependency on the sync — overlaps poll) ----
        {
            const __bf16* xp = Xb + (size_t)t * BB * EE;
#pragma unroll
            for (int it = 0; it < 8; ++it) {
                int idx = tid + it * 256;
                int b = idx >> 5, ch = idx & 31;
                *reinterpret_cast<bf16x8*>(&A[b * LDA + 512 + ch * 8]) =
                    *reinterpret_cast<const bf16x8*>(xp + (size_t)b * EE + ch * 8);
            }
        }

        if (s > 0) {
            // wait for all WGs of this direction to finish step s-1
            if (tid == 0) {
                while (__hip_atomic_load(&cnt[d * TT + s - 1], __ATOMIC_RELAXED,
                                         __HIP_MEMORY_SCOPE_AGENT) < NSL)
                    __builtin_amdgcn_s_sleep(1);
            }
            __syncthreads();
            // ---- stage h(t_prev): 8B agent-scope atomic loads (L2-bypass) ----
            const u64* hp = reinterpret_cast<const u64*>(hd + (size_t)tp * BB * HH);
#pragma unroll
            for (int it = 0; it < 32; ++it) {
                int idx = it * 256 + tid;
                int b = idx >> 7, k = idx & 127;      // k indexes 8B chunks (4 bf16)
                u64 v = __hip_atomic_load(hp + (size_t)b * (HH / 4) + k,
                                          __ATOMIC_RELAXED, __HIP_MEMORY_SCOPE_AGENT);
                *reinterpret_cast<u64*>(&A[b * LDA + k * 4]) = v;
            }
        }
        __syncthreads();

        // ---- MFMA: acc[mt] (16b x 16 gate-rows) over K ----
        f32x4 acc[4];
#pragma unroll
        for (int mt = 0; mt < 4; ++mt) acc[mt] = (f32x4){bias, bias, bias, bias};

        if (s == 0) {   // h_prev == 0: only the x part (kk = 16..23)
#pragma unroll
            for (int mt = 0; mt < 4; ++mt) {
                const __bf16* ab = &A[(mt * 16 + c) * LDA + kch * 8];
#pragma unroll
                for (int kk = 16; kk < NKK; ++kk) {
                    bf16x8 a = *reinterpret_cast<const bf16x8*>(ab + kk * 32);
                    acc[mt] = __builtin_amdgcn_mfma_f32_16x16x32_bf16(a, Bf[kk], acc[mt], 0, 0, 0);
                }
            }
        } else {
#pragma unroll
            for (int mt = 0; mt < 4; ++mt) {
                const __bf16* ab = &A[(mt * 16 + c) * LDA + kch * 8];
#pragma unroll
                for (int kk = 0; kk < NKK; ++kk) {
                    bf16x8 a = *reinterpret_cast<const bf16x8*>(ab + kk * 32);
                    acc[mt] = __builtin_amdgcn_mfma_f32_16x16x32_bf16(a, Bf[kk], acc[mt], 0, 0, 0);
                }
            }
        }

        // ---- gather i,f,g,o via xor-shuffles; activations; packed 8B h store ----
        __bf16* ho = hd + (size_t)t * BB * HH;
#pragma unroll
        for (int mt = 0; mt < 4; ++mt) {
#pragma unroll
            for (int r = 0; r < 4; ++r) {
                float v   = acc[mt][r];
                float t4  = __shfl_xor(v, 4);    // gate 1 (f) for lanes c<4
                float t8  = __shfl_xor(v, 8);    // gate 2 (g)
                float t12 = __shfl_xor(t4, 8);   // gate 3 (o)
                float ig = 1.f / (1.f + __expf(-v));
                float fg = 1.f / (1.f + __expf(-t4));
                float e2 = __expf(2.f * t8);
                float gg = 1.f - 2.f / (e2 + 1.f);      // tanh
                float og = 1.f / (1.f + __expf(-t12));
                float cn = fg * cs[mt][r] + ig * gg;
                cs[mt][r] = cn;
                float e2c = __expf(2.f * cn);
                float th  = 1.f - 2.f / (e2c + 1.f);
                float hv  = og * th;
                // pack units (U0+4q+0..3) for this b into one 8B store (lane c==0)
                float h1 = __shfl_xor(hv, 1);
                float h2 = __shfl_xor(hv, 2);
                float h3 = __shfl_xor(hv, 3);
                if (c == 0) {
                    bf16x4 hb;
                    hb[0] = (__bf16)hv; hb[1] = (__bf16)h1;
                    hb[2] = (__bf16)h2; hb[3] = (__bf16)h3;
                    u64 u = __builtin_bit_cast(u64, hb);
                    int b = mt * 16 + kch * 4 + r;
                    __hip_atomic_store(
                        reinterpret_cast<u64*>(ho + (size_t)b * HH + U0 + 4 * q), u,
                        __ATOMIC_RELAXED, __HIP_MEMORY_SCOPE_AGENT);
                }
            }
        }

        // release: drain stores to the coherence point, then bump the counter.
        asm volatile("s_waitcnt vmcnt(0)" ::: "memory");
        __syncthreads();
        if (tid == 0)
            __hip_atomic_fetch_add(&cnt[d * TT + s], 1, __ATOMIC_RELAXED,
                                   __HIP_MEMORY_SCOPE_AGENT);
    }
}

// ============================================================
// K2: emissions em[t][b][k] = [hf(t),hb(t)] . W_out[:,k] + b_out[k]
// ============================================================
__global__ __launch_bounds__(256) void em_kernel(const __bf16* __restrict__ h,
                                                 const float* __restrict__ W_out,
                                                 const float* __restrict__ b_out,
                                                 float* __restrict__ em) {
    const int t  = blockIdx.x;
    const int k  = threadIdx.x & 31;
    const int b8 = threadIdx.x >> 5;

    float acc[8];
#pragma unroll
    for (int i = 0; i < 8; ++i) acc[i] = b_out[k];

#pragma unroll
    for (int src = 0; src < 2; ++src) {
        const __bf16* hr = h + ((size_t)src * TT + t) * BB * HH;
        const float*  W  = W_out + (size_t)src * HH * KTAG;
        for (int jc = 0; jc < HH / 8; ++jc) {
            float w[8];
#pragma unroll
            for (int jj = 0; jj < 8; ++jj) w[jj] = W[(jc * 8 + jj) * KTAG + k];
#pragma unroll
            for (int i = 0; i < 8; ++i) {
                bf16x8 hv = *reinterpret_cast<const bf16x8*>(
                    hr + (size_t)(b8 * 8 + i) * HH + jc * 8);
#pragma unroll
                for (int jj = 0; jj < 8; ++jj) acc[i] += (float)hv[jj] * w[jj];
            }
        }
    }
#pragma unroll
    for (int i = 0; i < 8; ++i)
        em[((size_t)t * BB + (b8 * 8 + i)) * KTAG + k] = acc[i];
}

// ============================================================
// K3: CRF — sentence score + log-partition; out[b] = logZ - score.
// ============================================================
__global__ __launch_bounds__(64) void crf_kernel(const float* __restrict__ em,
                                                 const int* __restrict__ tags,
                                                 const float* __restrict__ masks,
                                                 const float* __restrict__ trans,
                                                 float* __restrict__ out) {
    __shared__ float tr[KTAG * KTAG];
    __shared__ float al[64];
    const int b    = blockIdx.x;
    const int lane = threadIdx.x;

#pragma unroll
    for (int ii = 0; ii < 16; ++ii) tr[lane + ii * 64] = trans[lane + ii * 64];
    __syncthreads();

    // ---- sentence (gold-path) score ----
    float part = 0.f, msum = 0.f;
    for (int t = lane; t < TT; t += 64) {
        int tg = tags[b * TT + t];
        float e = em[((size_t)t * BB + b) * KTAG + tg];
        if (t == 0) {
            part += tr[START_TAG * KTAG + tg] + e;
        } else {
            int tgp = tags[b * TT + t - 1];
            float m = masks[b * TT + t];
            part += m * (e + tr[tgp * KTAG + tg]);
        }
        msum += masks[b * TT + t];
    }
#pragma unroll
    for (int off = 32; off; off >>= 1) {
        part += __shfl_xor(part, off);
        msum += __shfl_xor(msum, off);
    }
    int   last_idx = (int)(msum + 0.5f) - 1;
    int   last_tag = tags[b * TT + last_idx];
    float score    = part + tr[last_tag * KTAG + END_TAG];

    // ---- log partition (forward algorithm) ----
    const int j    = lane & 31;
    const int half = lane >> 5;
    float alpha = tr[START_TAG * KTAG + j] + em[(size_t)b * KTAG + j];  // t = 0
    for (int t = 1; t < TT; ++t) {
        al[lane] = alpha;
        __syncthreads();
        float v[16], mx = -1e30f;
#pragma unroll
        for (int ii = 0; ii < 16; ++ii) {
            int i = half * 16 + ii;
            v[ii] = al[i] + tr[i * KTAG + j];
            mx = fmaxf(mx, v[ii]);
        }
        float sexp = 0.f;
#pragma unroll
        for (int ii = 0; ii < 16; ++ii) sexp += __expf(v[ii] - mx);
        float mo = __shfl_xor(mx, 32);
        float so = __shfl_xor(sexp, 32);
        float m2 = fmaxf(mx, mo);
        float st = sexp * __expf(mx - m2) + so * __expf(mo - m2);
        float e  = em[((size_t)t * BB + b) * KTAG + j];
        float na = e + m2 + __logf(st);
        float m  = masks[b * TT + t];
        alpha = na * m + alpha * (1.f - m);
        __syncthreads();
    }
    alpha += tr[j * KTAG + END_TAG];
    float m = alpha, ssum = 1.f;
#pragma unroll
    for (int off = 1; off < 32; off <<= 1) {
        float mo = __shfl_xor(m, off);
        float so = __shfl_xor(ssum, off);
        float m2 = fmaxf(m, mo);
        ssum = ssum * __expf(m - m2) + so * __expf(mo - m2);
        m = m2;
    }
    float logZ = m + __logf(ssum);
    if (lane == 0) out[b] = logZ - score;
}

// ============================================================
extern "C" void kernel_launch(void* const* d_in, const int* in_sizes, int n_in,
                              void* d_out, int out_size, void* d_ws, size_t ws_size,
                              hipStream_t stream) {
    const float* X     = (const float*)d_in[0];
    const int*   tags  = (const int*)d_in[1];
    const float* masks = (const float*)d_in[2];
    const float* Wih_f = (const float*)d_in[3];
    const float* Whh_f = (const float*)d_in[4];
    const float* bih_f = (const float*)d_in[5];
    const float* bhh_f = (const float*)d_in[6];
    const float* Wih_b = (const float*)d_in[7];
    const float* Whh_b = (const float*)d_in[8];
    const float* bih_b = (const float*)d_in[9];
    const float* bhh_b = (const float*)d_in[10];
    const float* W_out = (const float*)d_in[11];
    const float* b_out = (const float*)d_in[12];
    const float* trans = (const float*)d_in[13];
    float* out = (float*)d_out;

    if (ws_size < WS_NEED) return;  // fail cleanly rather than corrupt

    char*   ws  = (char*)d_ws;
    __bf16* Xb  = (__bf16*)(ws + OFF_XB);
    __bf16* h   = (__bf16*)(ws + OFF_H);
    float*  em  = (float*)(ws + OFF_EM);
    int*    cnt = (int*)(ws + OFF_CNT);

    hipMemsetAsync(cnt, 0, 2 * TT * sizeof(int), stream);

    prep_x<<<dim3((TT * BB * EE / 4) / 256), dim3(256), 0, stream>>>(X, Xb);

    void* args[] = {(void*)&Xb,
                    (void*)&Wih_f, (void*)&Whh_f, (void*)&bih_f, (void*)&bhh_f,
                    (void*)&Wih_b, (void*)&Whh_b, (void*)&bih_b, (void*)&bhh_b,
                    (void*)&h, (void*)&cnt};
    hipLaunchCooperativeKernel(rec_kernel, dim3(NWG), dim3(256), args, 0, stream);

    em_kernel<<<dim3(TT), dim3(256), 0, stream>>>(h, W_out, b_out, em);
    crf_kernel<<<dim3(BB), dim3(64), 0, stream>>>(em, tags, masks, trans, out);
}

// Round 3
// 4148.537 us; speedup vs baseline: 1.0130x; 1.0006x over previous
//
#include <hip/hip_runtime.h>
#include <hip/hip_bf16.h>

// ---------------- problem constants ----------------
#define TT   256   // sequence length
#define BB   64    // batch
#define EE   256   // input embedding
#define HH   512   // hidden
#define KTAG 32    // number of tags
#define START_TAG 30
#define END_TAG   31

// ---------------- recurrence decomposition ----------------
#define NSL  32            // workgroups per direction; each owns 16 hidden units
#define NWG  (2 * NSL)     // total workgroups (both directions in one grid)
#define NKK  24            // K-steps of 32: 16 for h (K=512) + 8 for x (K=256)
#define LDA  776           // padded LDS row (bf16 elems); 776*2B = 1552B (16B multiple)

typedef __attribute__((ext_vector_type(8))) __bf16 bf16x8;
typedef __attribute__((ext_vector_type(4))) __bf16 bf16x4;
typedef __attribute__((ext_vector_type(4))) float  f32x4;
typedef unsigned long long u64;

// ---------------- workspace layout (bytes) ----------------
#define OFF_XB  ((size_t)0)                              // Xb: TT*BB*EE bf16 = 8 MiB
#define OFF_H   ((size_t)TT * BB * EE * 2)               // h:  2*TT*BB*HH bf16 = 32 MiB
#define OFF_EM  (OFF_H + (size_t)2 * TT * BB * HH * 2)   // em: TT*BB*KTAG f32 = 2 MiB
#define OFF_CNT (OFF_EM + (size_t)TT * BB * KTAG * 4)    // flg: 2*64 ints (padded dirs)
#define WS_NEED (OFF_CNT + (size_t)2 * 64 * 4)

// ============================================================
// K0: X (fp32, [b][t][e]) -> Xb (bf16, [t][b][e])
// ============================================================
__global__ __launch_bounds__(256) void prep_x(const float* __restrict__ X,
                                              __bf16* __restrict__ Xb) {
    int i = blockIdx.x * 256 + threadIdx.x;   // one thread = 4 output elems
    int o = i * 4;                            // flat index into Xb
    int e  = o & (EE - 1);
    int tb = o >> 8;                          // EE = 256
    int b  = tb & (BB - 1);
    int t  = tb >> 6;                         // BB = 64
    const float4 v = *reinterpret_cast<const float4*>(X + ((size_t)b * TT + t) * EE + e);
    bf16x4 r;
    r[0] = (__bf16)v.x; r[1] = (__bf16)v.y; r[2] = (__bf16)v.z; r[3] = (__bf16)v.w;
    *reinterpret_cast<bf16x4*>(Xb + o) = r;
}

// ============================================================
// K1: persistent cooperative BiLSTM recurrence (bf16 MFMA).
// Cross-WG sync: per-WG epoch flags (plain relaxed agent stores, no RMW);
// every wave polls all 32 flags with one coalesced 128B load + __all,
// then proceeds straight to its h staging (no extra barrier).
// ============================================================
__global__ __launch_bounds__(256, 1) void rec_kernel(
    const __bf16* __restrict__ Xb,
    const float* __restrict__ Wih_f, const float* __restrict__ Whh_f,
    const float* __restrict__ bih_f, const float* __restrict__ bhh_f,
    const float* __restrict__ Wih_b, const float* __restrict__ Whh_b,
    const float* __restrict__ bih_b, const float* __restrict__ bhh_b,
    __bf16* __restrict__ h, int* __restrict__ flg) {
    __shared__ __bf16 A[BB * LDA];   // 99,328 B

    const int wg  = blockIdx.x;
    const int d   = wg >> 5;         // 0 = fwd, 1 = bwd
    const int sl  = wg & 31;
    const int U0  = sl * 16;         // first hidden unit of this WG
    const int tid = threadIdx.x;
    const int q   = tid >> 6;        // wave id (0..3)
    const int l   = tid & 63;        // lane
    const int c   = l & 15;          // MFMA col / A row-in-tile
    const int kch = l >> 4;          // MFMA k-chunk (0..3)

    const float* Wih = d ? Wih_b : Wih_f;
    const float* Whh = d ? Whh_b : Whh_f;
    const float* bih = d ? bih_b : bih_f;
    const float* bhh = d ? bhh_b : bhh_f;
    __bf16* hd = h + (size_t)d * TT * BB * HH;
    int* flgd = flg + d * 64;        // this direction's 32 flags (128B region)

    // this lane's gate row (column c of the wave's N=16 tile):
    // c = g*4 + u', unit = U0 + 4*q + u', global row = g*512 + unit
    const int g4  = c >> 2;
    const int up  = c & 3;
    const int row = g4 * HH + U0 + 4 * q + up;

    // ---- one-time: load B fragments (weights, bf16) into registers ----
    bf16x8 Bf[NKK];
#pragma unroll
    for (int kk = 0; kk < NKK; ++kk) {
        bf16x8 bv;
#pragma unroll
        for (int j = 0; j < 8; ++j) {
            int kb = kch * 8 + j;
            float w = (kk < 16) ? Whh[(size_t)row * HH + kk * 32 + kb]
                                : Wih[(size_t)row * EE + (kk - 16) * 32 + kb];
            bv[j] = (__bf16)w;
        }
        Bf[kk] = bv;
    }
    const float bias = bih[row] + bhh[row];

    // cell state for (b = mt*16 + kch*4 + r, unit = U0+4q+c); valid in lanes c<4
    f32x4 cs[4];
#pragma unroll
    for (int mt = 0; mt < 4; ++mt) cs[mt] = (f32x4){0.f, 0.f, 0.f, 0.f};

    for (int s = 0; s < TT; ++s) {
        const int t  = d ? (TT - 1 - s) : s;
        const int tp = d ? (t + 1) : (t - 1);

        // ---- stage x_t into LDS (independent of the sync) ----
        {
            const __bf16* xp = Xb + (size_t)t * BB * EE;
#pragma unroll
            for (int it = 0; it < 8; ++it) {
                int idx = tid + it * 256;
                int b = idx >> 5, ch = idx & 31;
                *reinterpret_cast<bf16x8*>(&A[b * LDA + 512 + ch * 8]) =
                    *reinterpret_cast<const bf16x8*>(xp + (size_t)b * EE + ch * 8);
            }
        }

        if (s > 0) {
            // ---- wave-autonomous poll: all 32 producer flags >= s ----
            for (;;) {
                int f = __hip_atomic_load(&flgd[l & 31], __ATOMIC_RELAXED,
                                          __HIP_MEMORY_SCOPE_AGENT);
                if (__all(f >= s)) break;
                __builtin_amdgcn_s_sleep(2);
            }
            // ---- stage h(t_prev): 8B agent-scope atomic loads (L2-bypass) ----
            const u64* hp = reinterpret_cast<const u64*>(hd + (size_t)tp * BB * HH);
#pragma unroll
            for (int it = 0; it < 32; ++it) {
                int idx = it * 256 + tid;
                int b = idx >> 7, k = idx & 127;      // k indexes 8B chunks (4 bf16)
                u64 v = __hip_atomic_load(hp + (size_t)b * (HH / 4) + k,
                                          __ATOMIC_RELAXED, __HIP_MEMORY_SCOPE_AGENT);
                *reinterpret_cast<u64*>(&A[b * LDA + k * 4]) = v;
            }
        }
        __syncthreads();

        // ---- MFMA: acc[mt] (16b x 16 gate-rows) over K ----
        f32x4 acc[4];
#pragma unroll
        for (int mt = 0; mt < 4; ++mt) acc[mt] = (f32x4){bias, bias, bias, bias};

        if (s == 0) {   // h_prev == 0: only the x part (kk = 16..23)
#pragma unroll
            for (int mt = 0; mt < 4; ++mt) {
                const __bf16* ab = &A[(mt * 16 + c) * LDA + kch * 8];
#pragma unroll
                for (int kk = 16; kk < NKK; ++kk) {
                    bf16x8 a = *reinterpret_cast<const bf16x8*>(ab + kk * 32);
                    acc[mt] = __builtin_amdgcn_mfma_f32_16x16x32_bf16(a, Bf[kk], acc[mt], 0, 0, 0);
                }
            }
        } else {
#pragma unroll
            for (int mt = 0; mt < 4; ++mt) {
                const __bf16* ab = &A[(mt * 16 + c) * LDA + kch * 8];
#pragma unroll
                for (int kk = 0; kk < NKK; ++kk) {
                    bf16x8 a = *reinterpret_cast<const bf16x8*>(ab + kk * 32);
                    acc[mt] = __builtin_amdgcn_mfma_f32_16x16x32_bf16(a, Bf[kk], acc[mt], 0, 0, 0);
                }
            }
        }

        // ---- gather i,f,g,o via xor-shuffles; activations; packed 8B h store ----
        __bf16* ho = hd + (size_t)t * BB * HH;
#pragma unroll
        for (int mt = 0; mt < 4; ++mt) {
#pragma unroll
            for (int r = 0; r < 4; ++r) {
                float v   = acc[mt][r];
                float t4  = __shfl_xor(v, 4);    // gate 1 (f) for lanes c<4
                float t8  = __shfl_xor(v, 8);    // gate 2 (g)
                float t12 = __shfl_xor(t4, 8);   // gate 3 (o)
                float ig = 1.f / (1.f + __expf(-v));
                float fg = 1.f / (1.f + __expf(-t4));
                float e2 = __expf(2.f * t8);
                float gg = 1.f - 2.f / (e2 + 1.f);      // tanh
                float og = 1.f / (1.f + __expf(-t12));
                float cn = fg * cs[mt][r] + ig * gg;
                cs[mt][r] = cn;
                float e2c = __expf(2.f * cn);
                float th  = 1.f - 2.f / (e2c + 1.f);
                float hv  = og * th;
                // pack units (U0+4q+0..3) for this b into one 8B store (lane c==0)
                float h1 = __shfl_xor(hv, 1);
                float h2 = __shfl_xor(hv, 2);
                float h3 = __shfl_xor(hv, 3);
                if (c == 0) {
                    bf16x4 hb;
                    hb[0] = (__bf16)hv; hb[1] = (__bf16)h1;
                    hb[2] = (__bf16)h2; hb[3] = (__bf16)h3;
                    u64 u = __builtin_bit_cast(u64, hb);
                    int b = mt * 16 + kch * 4 + r;
                    __hip_atomic_store(
                        reinterpret_cast<u64*>(ho + (size_t)b * HH + U0 + 4 * q), u,
                        __ATOMIC_RELAXED, __HIP_MEMORY_SCOPE_AGENT);
                }
            }
        }

        // release: drain this wave's stores, barrier, then publish epoch flag.
        asm volatile("s_waitcnt vmcnt(0)" ::: "memory");
        __syncthreads();
        if (tid == 0)
            __hip_atomic_store(&flgd[sl], s + 1, __ATOMIC_RELAXED,
                               __HIP_MEMORY_SCOPE_AGENT);
    }
}

// ============================================================
// K2: emissions em[t][b][k] = [hf(t),hb(t)] . W_out[:,k] + b_out[k]
// ============================================================
__global__ __launch_bounds__(256) void em_kernel(const __bf16* __restrict__ h,
                                                 const float* __restrict__ W_out,
                                                 const float* __restrict__ b_out,
                                                 float* __restrict__ em) {
    const int t  = blockIdx.x;
    const int k  = threadIdx.x & 31;
    const int b8 = threadIdx.x >> 5;

    float acc[8];
#pragma unroll
    for (int i = 0; i < 8; ++i) acc[i] = b_out[k];

#pragma unroll
    for (int src = 0; src < 2; ++src) {
        const __bf16* hr = h + ((size_t)src * TT + t) * BB * HH;
        const float*  W  = W_out + (size_t)src * HH * KTAG;
        for (int jc = 0; jc < HH / 8; ++jc) {
            float w[8];
#pragma unroll
            for (int jj = 0; jj < 8; ++jj) w[jj] = W[(jc * 8 + jj) * KTAG + k];
#pragma unroll
            for (int i = 0; i < 8; ++i) {
                bf16x8 hv = *reinterpret_cast<const bf16x8*>(
                    hr + (size_t)(b8 * 8 + i) * HH + jc * 8);
#pragma unroll
                for (int jj = 0; jj < 8; ++jj) acc[i] += (float)hv[jj] * w[jj];
            }
        }
    }
#pragma unroll
    for (int i = 0; i < 8; ++i)
        em[((size_t)t * BB + (b8 * 8 + i)) * KTAG + k] = acc[i];
}

// ============================================================
// K3: CRF — sentence score + log-partition; out[b] = logZ - score.
// ============================================================
__global__ __launch_bounds__(64) void crf_kernel(const float* __restrict__ em,
                                                 const int* __restrict__ tags,
                                                 const float* __restrict__ masks,
                                                 const float* __restrict__ trans,
                                                 float* __restrict__ out) {
    __shared__ float tr[KTAG * KTAG];
    __shared__ float al[64];
    const int b    = blockIdx.x;
    const int lane = threadIdx.x;

#pragma unroll
    for (int ii = 0; ii < 16; ++ii) tr[lane + ii * 64] = trans[lane + ii * 64];
    __syncthreads();

    // ---- sentence (gold-path) score ----
    float part = 0.f, msum = 0.f;
    for (int t = lane; t < TT; t += 64) {
        int tg = tags[b * TT + t];
        float e = em[((size_t)t * BB + b) * KTAG + tg];
        if (t == 0) {
            part += tr[START_TAG * KTAG + tg] + e;
        } else {
            int tgp = tags[b * TT + t - 1];
            float m = masks[b * TT + t];
            part += m * (e + tr[tgp * KTAG + tg]);
        }
        msum += masks[b * TT + t];
    }
#pragma unroll
    for (int off = 32; off; off >>= 1) {
        part += __shfl_xor(part, off);
        msum += __shfl_xor(msum, off);
    }
    int   last_idx = (int)(msum + 0.5f) - 1;
    int   last_tag = tags[b * TT + last_idx];
    float score    = part + tr[last_tag * KTAG + END_TAG];

    // ---- log partition (forward algorithm) ----
    const int j    = lane & 31;
    const int half = lane >> 5;
    float alpha = tr[START_TAG * KTAG + j] + em[(size_t)b * KTAG + j];  // t = 0
    for (int t = 1; t < TT; ++t) {
        al[lane] = alpha;
        __syncthreads();
        float v[16], mx = -1e30f;
#pragma unroll
        for (int ii = 0; ii < 16; ++ii) {
            int i = half * 16 + ii;
            v[ii] = al[i] + tr[i * KTAG + j];
            mx = fmaxf(mx, v[ii]);
        }
        float sexp = 0.f;
#pragma unroll
        for (int ii = 0; ii < 16; ++ii) sexp += __expf(v[ii] - mx);
        float mo = __shfl_xor(mx, 32);
        float so = __shfl_xor(sexp, 32);
        float m2 = fmaxf(mx, mo);
        float st = sexp * __expf(mx - m2) + so * __expf(mo - m2);
        float e  = em[((size_t)t * BB + b) * KTAG + j];
        float na = e + m2 + __logf(st);
        float m  = masks[b * TT + t];
        alpha = na * m + alpha * (1.f - m);
        __syncthreads();
    }
    alpha += tr[j * KTAG + END_TAG];
    float m = alpha, ssum = 1.f;
#pragma unroll
    for (int off = 1; off < 32; off <<= 1) {
        float mo = __shfl_xor(m, off);
        float so = __shfl_xor(ssum, off);
        float m2 = fmaxf(m, mo);
        ssum = ssum * __expf(m - m2) + so * __expf(mo - m2);
        m = m2;
    }
    float logZ = m + __logf(ssum);
    if (lane == 0) out[b] = logZ - score;
}

// ============================================================
extern "C" void kernel_launch(void* const* d_in, const int* in_sizes, int n_in,
                              void* d_out, int out_size, void* d_ws, size_t ws_size,
                              hipStream_t stream) {
    const float* X     = (const float*)d_in[0];
    const int*   tags  = (const int*)d_in[1];
    const float* masks = (const float*)d_in[2];
    const float* Wih_f = (const float*)d_in[3];
    const float* Whh_f = (const float*)d_in[4];
    const float* bih_f = (const float*)d_in[5];
    const float* bhh_f = (const float*)d_in[6];
    const float* Wih_b = (const float*)d_in[7];
    const float* Whh_b = (const float*)d_in[8];
    const float* bih_b = (const float*)d_in[9];
    const float* bhh_b = (const float*)d_in[10];
    const float* W_out = (const float*)d_in[11];
    const float* b_out = (const float*)d_in[12];
    const float* trans = (const float*)d_in[13];
    float* out = (float*)d_out;

    if (ws_size < WS_NEED) return;  // fail cleanly rather than corrupt

    char*   ws  = (char*)d_ws;
    __bf16* Xb  = (__bf16*)(ws + OFF_XB);
    __bf16* h   = (__bf16*)(ws + OFF_H);
    float*  em  = (float*)(ws + OFF_EM);
    int*    flg = (int*)(ws + OFF_CNT);

    hipMemsetAsync(flg, 0, 2 * 64 * sizeof(int), stream);

    prep_x<<<dim3((TT * BB * EE / 4) / 256), dim3(256), 0, stream>>>(X, Xb);

    void* args[] = {(void*)&Xb,
                    (void*)&Wih_f, (void*)&Whh_f, (void*)&bih_f, (void*)&bhh_f,
                    (void*)&Wih_b, (void*)&Whh_b, (void*)&bih_b, (void*)&bhh_b,
                    (void*)&h, (void*)&flg};
    hipLaunchCooperativeKernel(rec_kernel, dim3(NWG), dim3(256), args, 0, stream);

    em_kernel<<<dim3(TT), dim3(256), 0, stream>>>(h, W_out, b_out, em);
    crf_kernel<<<dim3(BB), dim3(64), 0, stream>>>(em, tags, masks, trans, out);
}

// Round 4
// 2897.890 us; speedup vs baseline: 1.4502x; 1.4316x over previous
//
#include <hip/hip_runtime.h>
#include <hip/hip_bf16.h>

// ---------------- problem constants ----------------
#define TT   256   // sequence length
#define BB   64    // batch
#define EE   256   // input embedding
#define HH   512   // hidden
#define KTAG 32    // number of tags
#define START_TAG 30
#define END_TAG   31

// ---------------- recurrence decomposition ----------------
#define NSL  32            // workgroups per direction; each owns 16 hidden units
#define NWG  (2 * NSL)     // total workgroups (both directions in one grid)
#define NKK  24            // K-steps of 32: 16 for h (K=512) + 8 for x (K=256)
#define LDA  776           // padded LDS row (bf16 elems); 776*2B = 1552B (16B multiple)

typedef __attribute__((ext_vector_type(8))) __bf16 bf16x8;
typedef __attribute__((ext_vector_type(4))) __bf16 bf16x4;
typedef __attribute__((ext_vector_type(4))) float  f32x4;
typedef unsigned long long u64;

// ---------------- workspace layout (bytes) ----------------
#define OFF_XB  ((size_t)0)                              // Xb: TT*BB*EE bf16 = 8 MiB
#define OFF_H   ((size_t)TT * BB * EE * 2)               // h:  2*TT*BB*HH bf16 = 32 MiB
#define OFF_EM  (OFF_H + (size_t)2 * TT * BB * HH * 2)   // em: TT*BB*KTAG f32 = 2 MiB
#define OFF_CNT (OFF_EM + (size_t)TT * BB * KTAG * 4)    // flg: 2*256 ints (per-wave flags)
#define WS_NEED (OFF_CNT + (size_t)2 * 256 * 4)

// ============================================================
// K0: X (fp32, [b][t][e]) -> Xb (bf16, [t][b][e])
// ============================================================
__global__ __launch_bounds__(256) void prep_x(const float* __restrict__ X,
                                              __bf16* __restrict__ Xb) {
    int i = blockIdx.x * 256 + threadIdx.x;   // one thread = 4 output elems
    int o = i * 4;                            // flat index into Xb
    int e  = o & (EE - 1);
    int tb = o >> 8;                          // EE = 256
    int b  = tb & (BB - 1);
    int t  = tb >> 6;                         // BB = 64
    const float4 v = *reinterpret_cast<const float4*>(X + ((size_t)b * TT + t) * EE + e);
    bf16x4 r;
    r[0] = (__bf16)v.x; r[1] = (__bf16)v.y; r[2] = (__bf16)v.z; r[3] = (__bf16)v.w;
    *reinterpret_cast<bf16x4*>(Xb + o) = r;
}

// ============================================================
// K1: persistent cooperative BiLSTM recurrence (bf16 MFMA).
// Protocol per step:
//   producer wave: h stores (agent-scope sc-flagged) -> wave vmcnt(0)
//                  -> per-WAVE flag publish (no end barrier on critical path)
//   consumer wave: poll 128 per-wave flags -> PLAIN pipelined dwordx4 h loads
//                  (safe: first-touch lines, data already at coherence point;
//                   L2-amortized across the XCD) -> LDS -> h-MFMAs.
// x-part of the next step's gates is computed at the END of the current step
// (software pipeline), so it's off the inter-step critical path.
// ============================================================
__global__ __launch_bounds__(256, 1) void rec_kernel(
    const __bf16* __restrict__ Xb,
    const float* __restrict__ Wih_f, const float* __restrict__ Whh_f,
    const float* __restrict__ bih_f, const float* __restrict__ bhh_f,
    const float* __restrict__ Wih_b, const float* __restrict__ Whh_b,
    const float* __restrict__ bih_b, const float* __restrict__ bhh_b,
    __bf16* __restrict__ h, int* __restrict__ flg) {
    __shared__ __bf16 A[BB * LDA];   // 99,328 B

    const int wg  = blockIdx.x;
    const int d   = wg >> 5;         // 0 = fwd, 1 = bwd
    const int sl  = wg & 31;
    const int U0  = sl * 16;         // first hidden unit of this WG
    const int tid = threadIdx.x;
    const int q   = tid >> 6;        // wave id (0..3)
    const int l   = tid & 63;        // lane
    const int c   = l & 15;          // MFMA col / A row-in-tile
    const int kch = l >> 4;          // MFMA k-chunk (0..3)

    const float* Wih = d ? Wih_b : Wih_f;
    const float* Whh = d ? Whh_b : Whh_f;
    const float* bih = d ? bih_b : bih_f;
    const float* bhh = d ? bhh_b : bhh_f;
    __bf16* hd = h + (size_t)d * TT * BB * HH;
    int* flgd = flg + d * 256;       // this direction's 128 per-wave flags

    // this lane's gate row (column c of the wave's N=16 tile):
    // c = g*4 + u', unit = U0 + 4*q + u', global row = g*512 + unit
    const int g4  = c >> 2;
    const int up  = c & 3;
    const int row = g4 * HH + U0 + 4 * q + up;

    // ---- one-time: load B fragments (weights, bf16) into registers ----
    bf16x8 Bf[NKK];
#pragma unroll
    for (int kk = 0; kk < NKK; ++kk) {
        bf16x8 bv;
#pragma unroll
        for (int j = 0; j < 8; ++j) {
            int kb = kch * 8 + j;
            float w = (kk < 16) ? Whh[(size_t)row * HH + kk * 32 + kb]
                                : Wih[(size_t)row * EE + (kk - 16) * 32 + kb];
            bv[j] = (__bf16)w;
        }
        Bf[kk] = bv;
    }
    const float bias = bih[row] + bhh[row];

    // cell state for (b = mt*16 + kch*4 + r, unit = U0+4q+c); valid in lanes c<4
    f32x4 cs[4];
#pragma unroll
    for (int mt = 0; mt < 4; ++mt) cs[mt] = (f32x4){0.f, 0.f, 0.f, 0.f};

    f32x4 acc[4];

    // ---- prologue: stage x(t0), barrier, acc = bias + x-part ----
    {
        const int t0 = d ? (TT - 1) : 0;
        const __bf16* xp = Xb + (size_t)t0 * BB * EE;
#pragma unroll
        for (int it = 0; it < 8; ++it) {
            int idx = tid + it * 256;
            int b = idx >> 5, ch = idx & 31;
            *reinterpret_cast<bf16x8*>(&A[b * LDA + 512 + ch * 8]) =
                *reinterpret_cast<const bf16x8*>(xp + (size_t)b * EE + ch * 8);
        }
    }
    __syncthreads();
#pragma unroll
    for (int mt = 0; mt < 4; ++mt) {
        acc[mt] = (f32x4){bias, bias, bias, bias};
        const __bf16* ab = &A[(mt * 16 + c) * LDA + kch * 8];
#pragma unroll
        for (int kk = 16; kk < NKK; ++kk) {
            bf16x8 a = *reinterpret_cast<const bf16x8*>(ab + kk * 32);
            acc[mt] = __builtin_amdgcn_mfma_f32_16x16x32_bf16(a, Bf[kk], acc[mt], 0, 0, 0);
        }
    }

    for (int s = 0; s < TT; ++s) {
        const int t  = d ? (TT - 1 - s) : s;
        const int tp = d ? (t + 1) : (t - 1);

        if (s > 0) {
            // ---- wave-autonomous poll: all 128 producer wave-flags >= s ----
            for (;;) {
                int f0 = __hip_atomic_load(&flgd[l], __ATOMIC_RELAXED,
                                           __HIP_MEMORY_SCOPE_AGENT);
                int f1 = __hip_atomic_load(&flgd[64 + l], __ATOMIC_RELAXED,
                                           __HIP_MEMORY_SCOPE_AGENT);
                if (__all(f0 >= s && f1 >= s)) break;
                __builtin_amdgcn_s_sleep(2);
            }
            asm volatile("" ::: "memory");  // fence: keep h loads below the poll

            // ---- stage h(t_prev): PLAIN pipelined 16B loads -> LDS ----
            const __bf16* hp = hd + (size_t)tp * BB * HH;
#pragma unroll
            for (int it = 0; it < 16; ++it) {
                int chunk = it * 256 + tid;
                int b = chunk >> 6, k = chunk & 63;   // 64 chunks (16B) per batch row
                *reinterpret_cast<bf16x8*>(&A[b * LDA + k * 8]) =
                    *reinterpret_cast<const bf16x8*>(hp + (size_t)chunk * 8);
            }
        }
        __syncthreads();   // h-region of A complete

        if (s > 0) {
            // ---- h-part MFMAs (kk = 0..15) ----
#pragma unroll
            for (int mt = 0; mt < 4; ++mt) {
                const __bf16* ab = &A[(mt * 16 + c) * LDA + kch * 8];
#pragma unroll
                for (int kk = 0; kk < 16; ++kk) {
                    bf16x8 a = *reinterpret_cast<const bf16x8*>(ab + kk * 32);
                    acc[mt] = __builtin_amdgcn_mfma_f32_16x16x32_bf16(a, Bf[kk], acc[mt], 0, 0, 0);
                }
            }
        }

        // ---- gather i,f,g,o via xor-shuffles; activations; packed 8B h store ----
        __bf16* ho = hd + (size_t)t * BB * HH;
#pragma unroll
        for (int mt = 0; mt < 4; ++mt) {
#pragma unroll
            for (int r = 0; r < 4; ++r) {
                float v   = acc[mt][r];
                float t4  = __shfl_xor(v, 4);    // gate 1 (f) for lanes c<4
                float t8  = __shfl_xor(v, 8);    // gate 2 (g)
                float t12 = __shfl_xor(t4, 8);   // gate 3 (o)
                float ig = 1.f / (1.f + __expf(-v));
                float fg = 1.f / (1.f + __expf(-t4));
                float e2 = __expf(2.f * t8);
                float gg = 1.f - 2.f / (e2 + 1.f);      // tanh
                float og = 1.f / (1.f + __expf(-t12));
                float cn = fg * cs[mt][r] + ig * gg;
                cs[mt][r] = cn;
                float e2c = __expf(2.f * cn);
                float th  = 1.f - 2.f / (e2c + 1.f);
                float hv  = og * th;
                // pack units (U0+4q+0..3) for this b into one 8B store (lane c==0)
                float h1 = __shfl_xor(hv, 1);
                float h2 = __shfl_xor(hv, 2);
                float h3 = __shfl_xor(hv, 3);
                if (c == 0) {
                    bf16x4 hb;
                    hb[0] = (__bf16)hv; hb[1] = (__bf16)h1;
                    hb[2] = (__bf16)h2; hb[3] = (__bf16)h3;
                    u64 u = __builtin_bit_cast(u64, hb);
                    int b = mt * 16 + kch * 4 + r;
                    __hip_atomic_store(
                        reinterpret_cast<u64*>(ho + (size_t)b * HH + U0 + 4 * q), u,
                        __ATOMIC_RELAXED, __HIP_MEMORY_SCOPE_AGENT);
                }
            }
        }

        // per-WAVE release: drain this wave's stores, publish this wave's flag.
        asm volatile("s_waitcnt vmcnt(0)" ::: "memory");
        if (l == 0)
            __hip_atomic_store(&flgd[sl * 4 + q], s + 1, __ATOMIC_RELAXED,
                               __HIP_MEMORY_SCOPE_AGENT);

        if (s < TT - 1) {
            // ---- stage x(t_next) (x-region of A; no reader until after barrier) ----
            const int tn = d ? (TT - 2 - s) : (s + 1);
            const __bf16* xp = Xb + (size_t)tn * BB * EE;
#pragma unroll
            for (int it = 0; it < 8; ++it) {
                int idx = tid + it * 256;
                int b = idx >> 5, ch = idx & 31;
                *reinterpret_cast<bf16x8*>(&A[b * LDA + 512 + ch * 8]) =
                    *reinterpret_cast<const bf16x8*>(xp + (size_t)b * EE + ch * 8);
            }
        }
        __syncthreads();   // x-region ready; all waves done reading h-region

        if (s < TT - 1) {
            // ---- pre-accumulate next step's x-part: acc = bias + x-MFMAs ----
#pragma unroll
            for (int mt = 0; mt < 4; ++mt) {
                acc[mt] = (f32x4){bias, bias, bias, bias};
                const __bf16* ab = &A[(mt * 16 + c) * LDA + kch * 8];
#pragma unroll
                for (int kk = 16; kk < NKK; ++kk) {
                    bf16x8 a = *reinterpret_cast<const bf16x8*>(ab + kk * 32);
                    acc[mt] = __builtin_amdgcn_mfma_f32_16x16x32_bf16(a, Bf[kk], acc[mt], 0, 0, 0);
                }
            }
        }
    }
}

// ============================================================
// K2: emissions em[t][b][k] = [hf(t),hb(t)] . W_out[:,k] + b_out[k]
// ============================================================
__global__ __launch_bounds__(256) void em_kernel(const __bf16* __restrict__ h,
                                                 const float* __restrict__ W_out,
                                                 const float* __restrict__ b_out,
                                                 float* __restrict__ em) {
    const int t  = blockIdx.x;
    const int k  = threadIdx.x & 31;
    const int b8 = threadIdx.x >> 5;

    float acc[8];
#pragma unroll
    for (int i = 0; i < 8; ++i) acc[i] = b_out[k];

#pragma unroll
    for (int src = 0; src < 2; ++src) {
        const __bf16* hr = h + ((size_t)src * TT + t) * BB * HH;
        const float*  W  = W_out + (size_t)src * HH * KTAG;
        for (int jc = 0; jc < HH / 8; ++jc) {
            float w[8];
#pragma unroll
            for (int jj = 0; jj < 8; ++jj) w[jj] = W[(jc * 8 + jj) * KTAG + k];
#pragma unroll
            for (int i = 0; i < 8; ++i) {
                bf16x8 hv = *reinterpret_cast<const bf16x8*>(
                    hr + (size_t)(b8 * 8 + i) * HH + jc * 8);
#pragma unroll
                for (int jj = 0; jj < 8; ++jj) acc[i] += (float)hv[jj] * w[jj];
            }
        }
    }
#pragma unroll
    for (int i = 0; i < 8; ++i)
        em[((size_t)t * BB + (b8 * 8 + i)) * KTAG + k] = acc[i];
}

// ============================================================
// K3: CRF — sentence score + log-partition; out[b] = logZ - score.
// ============================================================
__global__ __launch_bounds__(64) void crf_kernel(const float* __restrict__ em,
                                                 const int* __restrict__ tags,
                                                 const float* __restrict__ masks,
                                                 const float* __restrict__ trans,
                                                 float* __restrict__ out) {
    __shared__ float tr[KTAG * KTAG];
    __shared__ float al[64];
    const int b    = blockIdx.x;
    const int lane = threadIdx.x;

#pragma unroll
    for (int ii = 0; ii < 16; ++ii) tr[lane + ii * 64] = trans[lane + ii * 64];
    __syncthreads();

    // ---- sentence (gold-path) score ----
    float part = 0.f, msum = 0.f;
    for (int t = lane; t < TT; t += 64) {
        int tg = tags[b * TT + t];
        float e = em[((size_t)t * BB + b) * KTAG + tg];
        if (t == 0) {
            part += tr[START_TAG * KTAG + tg] + e;
        } else {
            int tgp = tags[b * TT + t - 1];
            float m = masks[b * TT + t];
            part += m * (e + tr[tgp * KTAG + tg]);
        }
        msum += masks[b * TT + t];
    }
#pragma unroll
    for (int off = 32; off; off >>= 1) {
        part += __shfl_xor(part, off);
        msum += __shfl_xor(msum, off);
    }
    int   last_idx = (int)(msum + 0.5f) - 1;
    int   last_tag = tags[b * TT + last_idx];
    float score    = part + tr[last_tag * KTAG + END_TAG];

    // ---- log partition (forward algorithm) ----
    const int j    = lane & 31;
    const int half = lane >> 5;
    float alpha = tr[START_TAG * KTAG + j] + em[(size_t)b * KTAG + j];  // t = 0
    for (int t = 1; t < TT; ++t) {
        al[lane] = alpha;
        __syncthreads();
        float v[16], mx = -1e30f;
#pragma unroll
        for (int ii = 0; ii < 16; ++ii) {
            int i = half * 16 + ii;
            v[ii] = al[i] + tr[i * KTAG + j];
            mx = fmaxf(mx, v[ii]);
        }
        float sexp = 0.f;
#pragma unroll
        for (int ii = 0; ii < 16; ++ii) sexp += __expf(v[ii] - mx);
        float mo = __shfl_xor(mx, 32);
        float so = __shfl_xor(sexp, 32);
        float m2 = fmaxf(mx, mo);
        float st = sexp * __expf(mx - m2) + so * __expf(mo - m2);
        float e  = em[((size_t)t * BB + b) * KTAG + j];
        float na = e + m2 + __logf(st);
        float m  = masks[b * TT + t];
        alpha = na * m + alpha * (1.f - m);
        __syncthreads();
    }
    alpha += tr[j * KTAG + END_TAG];
    float m = alpha, ssum = 1.f;
#pragma unroll
    for (int off = 1; off < 32; off <<= 1) {
        float mo = __shfl_xor(m, off);
        float so = __shfl_xor(ssum, off);
        float m2 = fmaxf(m, mo);
        ssum = ssum * __expf(m - m2) + so * __expf(mo - m2);
        m = m2;
    }
    float logZ = m + __logf(ssum);
    if (lane == 0) out[b] = logZ - score;
}

// ============================================================
extern "C" void kernel_launch(void* const* d_in, const int* in_sizes, int n_in,
                              void* d_out, int out_size, void* d_ws, size_t ws_size,
                              hipStream_t stream) {
    const float* X     = (const float*)d_in[0];
    const int*   tags  = (const int*)d_in[1];
    const float* masks = (const float*)d_in[2];
    const float* Wih_f = (const float*)d_in[3];
    const float* Whh_f = (const float*)d_in[4];
    const float* bih_f = (const float*)d_in[5];
    const float* bhh_f = (const float*)d_in[6];
    const float* Wih_b = (const float*)d_in[7];
    const float* Whh_b = (const float*)d_in[8];
    const float* bih_b = (const float*)d_in[9];
    const float* bhh_b = (const float*)d_in[10];
    const float* W_out = (const float*)d_in[11];
    const float* b_out = (const float*)d_in[12];
    const float* trans = (const float*)d_in[13];
    float* out = (float*)d_out;

    if (ws_size < WS_NEED) return;  // fail cleanly rather than corrupt

    char*   ws  = (char*)d_ws;
    __bf16* Xb  = (__bf16*)(ws + OFF_XB);
    __bf16* h   = (__bf16*)(ws + OFF_H);
    float*  em  = (float*)(ws + OFF_EM);
    int*    flg = (int*)(ws + OFF_CNT);

    hipMemsetAsync(flg, 0, 2 * 256 * sizeof(int), stream);

    prep_x<<<dim3((TT * BB * EE / 4) / 256), dim3(256), 0, stream>>>(X, Xb);

    void* args[] = {(void*)&Xb,
                    (void*)&Wih_f, (void*)&Whh_f, (void*)&bih_f, (void*)&bhh_f,
                    (void*)&Wih_b, (void*)&Whh_b, (void*)&bih_b, (void*)&bhh_b,
                    (void*)&h, (void*)&flg};
    hipLaunchCooperativeKernel(rec_kernel, dim3(NWG), dim3(256), args, 0, stream);

    em_kernel<<<dim3(TT), dim3(256), 0, stream>>>(h, W_out, b_out, em);
    crf_kernel<<<dim3(BB), dim3(64), 0, stream>>>(em, tags, masks, trans, out);
}